// Round 5
// baseline (43.957 us; speedup 1.0000x reference)
//
#include <hip/hip_runtime.h>

// YOLO decode + 8-elem/thread register bitonic sort + box-level greedy NMS.
// One block (256 threads) per batch item. S=7,B=2,C=20 -> 98 boxes, 1960 entries.

constexpr int S_  = 7;
constexpr int Cc  = 20;
constexpr int NBOX  = 98;
constexpr int NENT  = 1960;
constexpr int NPAD  = 2048;
constexpr int LPRED = 1470;
constexpr int BATCH = 16;
constexpr int NT    = 256;
constexpr float IOU_THR_  = 0.1f;
constexpr float PROB_THR_ = 8e-25f;

__device__ __forceinline__ unsigned long long rl64(unsigned long long v, int l)
{
    unsigned lo = (unsigned)__builtin_amdgcn_readlane((int)(unsigned)v, l);
    unsigned hi = (unsigned)__builtin_amdgcn_readlane((int)(unsigned)(v >> 32), l);
    return ((unsigned long long)hi << 32) | lo;
}

__global__ __launch_bounds__(256)
void yolo_nms_kernel(const float* __restrict__ pred_all, float* __restrict__ out)
{
    const int b    = blockIdx.x;
    const int tid  = threadIdx.x;
    const int wid  = tid >> 6, lane = tid & 63;
    const float* pred = pred_all + b * LPRED;

    __shared__ float s_pred[LPRED];
    __shared__ unsigned long long ex[NPAD];       // SoA exchange: ex[i*NT + t]
    __shared__ float bXh[NBOX], bXl[NBOX], bYh[NBOX], bYl[NBOX], bA[NBOX];
    __shared__ float4 bBox[NBOX];
    __shared__ int   bCls[NBOX];
    __shared__ unsigned long long iouRow[NBOX * 2];
    __shared__ int firstpos[NBOX];
    __shared__ int boxorder[NBOX];
    __shared__ int kept[NBOX];
    __shared__ int s_nvalid;

    // ---- stage prediction + init ----
    for (int i = tid; i < LPRED; i += NT) s_pred[i] = pred[i];
    if (tid == 0) s_nvalid = 0;
    if (tid < NBOX) { kept[tid] = 0; firstpos[tid] = 0x7FFFFFFF; }
    __syncthreads();

    // ---- decode 98 boxes (reference float32 op order) + first-class-over-thr ----
    if (tid < NBOX) {
        const int bo = tid, cell = bo >> 1;
        const int ci = cell / S_, cj = cell % S_;
        const float bx = s_pred[1078 + bo * 4 + 0];
        const float by = s_pred[1078 + bo * 4 + 1];
        const float bw = s_pred[1078 + bo * 4 + 2];
        const float bh = s_pred[1078 + bo * 4 + 3];
        const float x = (bx + (float)ci) / 7.0f * 448.0f;
        const float y = (by + (float)cj) / 7.0f * 448.0f;
        const float w = bw * bw * 448.0f;
        const float h = bh * bh * 448.0f;
        bBox[bo] = make_float4(x, y, w, h);
        bXh[bo] = x + 0.5f * w;  bXl[bo] = x - 0.5f * w;
        bYh[bo] = y + 0.5f * h;  bYl[bo] = y - 0.5f * h;
        bA[bo]  = w * h;
        const float conf = s_pred[980 + bo];
        int cls = 0;
        for (int c = 0; c < Cc; ++c)
            if (s_pred[cell * Cc + c] * conf >= PROB_THR_) { cls = c; break; }
        bCls[bo] = cls;
    }

    // ---- build 8 sort keys per thread into registers ----
    // key = (prob_bits<<32) | (0xFFFFFFFF - idx); pads (idx>=NENT) = 0.
    unsigned long long e[8];
    #pragma unroll
    for (int i = 0; i < 8; ++i) {
        const int ee = tid * 8 + i;
        unsigned long long key = 0ull;
        if (ee < NENT) {
            const int bo = ee / Cc, c = ee - bo * Cc, cell = bo >> 1;
            const float ep = s_pred[cell * Cc + c] * s_pred[980 + bo];
            key = (unsigned long long)(0xFFFFFFFFu - (unsigned)ee);
            if (ep >= PROB_THR_)
                key |= ((unsigned long long)__float_as_uint(ep) << 32);
        }
        e[i] = key;
    }
    __syncthreads();              // decode results visible

    // ---- pairwise IoU rows via ballot ----
    for (int r = wid; r < NBOX; r += 4) {
        const float rXh = bXh[r], rXl = bXl[r], rYh = bYh[r], rYl = bYl[r], rA = bA[r];
        bool s1 = false, s2 = false;
        {
            const int j = lane;
            const float tb = fminf(rXh, bXh[j]) - fmaxf(rXl, bXl[j]);
            const float lr = fminf(rYh, bYh[j]) - fmaxf(rYl, bYl[j]);
            const float inter = (tb < 0.0f || lr < 0.0f) ? 0.0f : tb * lr;
            const float iou = inter / (rA + bA[j] - inter);   // 0/0 -> NaN -> false
            s1 = (iou > IOU_THR_);
        }
        if (lane + 64 < NBOX) {
            const int j = lane + 64;
            const float tb = fminf(rXh, bXh[j]) - fmaxf(rXl, bXl[j]);
            const float lr = fminf(rYh, bYh[j]) - fmaxf(rYl, bYl[j]);
            const float inter = (tb < 0.0f || lr < 0.0f) ? 0.0f : tb * lr;
            const float iou = inter / (rA + bA[j] - inter);
            s2 = (iou > IOU_THR_);
        }
        const unsigned long long m1 = __ballot(s1);
        const unsigned long long m2 = __ballot(s2);
        if (lane == 0) { iouRow[r * 2] = m1; iouRow[r * 2 + 1] = m2; }
    }

    // ---- bitonic sort, descending over global idx = 8*tid + i ----
    auto CE = [&](int i, int j, bool desc) {
        const unsigned long long a = e[i], c = e[j];
        const unsigned long long mx = a > c ? a : c;
        const unsigned long long mn = a > c ? c : a;
        e[i] = desc ? mx : mn;
        e[j] = desc ? mn : mx;
    };

    // in-thread build stages k=2,4,8 (dirs depend only on i / thread parity)
    CE(0,1,true); CE(2,3,false); CE(4,5,true); CE(6,7,false);           // k=2
    CE(0,2,true); CE(1,3,true);  CE(4,6,false); CE(5,7,false);          // k=4 js=2
    CE(0,1,true); CE(2,3,true);  CE(4,5,false); CE(6,7,false);          // k=4 js=1
    {
        const bool d8 = ((tid & 1) == 0);                               // k=8
        CE(0,4,d8); CE(1,5,d8); CE(2,6,d8); CE(3,7,d8);
        CE(0,2,d8); CE(1,3,d8); CE(4,6,d8); CE(5,7,d8);
        CE(0,1,d8); CE(2,3,d8); CE(4,5,d8); CE(6,7,d8);
    }

    // cross-thread stages k=16..2048
    for (int k = 16; k <= NPAD; k <<= 1) {
        const bool descT = ((tid & (k >> 3)) == 0);
        for (int js = k >> 1; js >= 8; js >>= 1) {
            const int jt = js >> 3;                       // thread-pair stride
            const bool keep_max = (descT == ((tid & jt) == 0));
            #pragma unroll
            for (int i = 0; i < 8; ++i) ex[i * NT + tid] = e[i];
            if (jt >= 64) __syncthreads();                // cross-wave RAW
            else asm volatile("" ::: "memory");           // same wave: DS in-order
            const int pt = tid ^ jt;
            unsigned long long p[8];
            #pragma unroll
            for (int i = 0; i < 8; ++i) p[i] = ex[i * NT + pt];
            #pragma unroll
            for (int i = 0; i < 8; ++i) {
                const unsigned long long mx = e[i] > p[i] ? e[i] : p[i];
                const unsigned long long mn = e[i] > p[i] ? p[i] : e[i];
                e[i] = keep_max ? mx : mn;
            }
            if (jt >= 64) __syncthreads();                // cross-wave WAR
            else asm volatile("" ::: "memory");
        }
        // js=4,2,1 in-thread merge, uniform direction per thread
        CE(0,4,descT); CE(1,5,descT); CE(2,6,descT); CE(3,7,descT);
        CE(0,2,descT); CE(1,3,descT); CE(4,6,descT); CE(5,7,descT);
        CE(0,1,descT); CE(2,3,descT); CE(4,5,descT); CE(6,7,descT);
    }

    // ---- per-box first positive-prob sorted position (from registers) ----
    #pragma unroll
    for (int i = 0; i < 8; ++i) {
        if (e[i] >> 32)
            atomicMin(&firstpos[(int)(0xFFFFFFFFu - (unsigned)e[i]) / Cc],
                      tid * 8 + i);
    }
    __syncthreads();

    // ---- rank boxes by firstpos (distinct -> permutation) ----
    if (tid < NBOX) {
        const int fp = firstpos[tid];
        if (fp != 0x7FFFFFFF) {
            int r = 0;
            for (int b2 = 0; b2 < NBOX; ++b2) r += (firstpos[b2] < fp) ? 1 : 0;
            boxorder[r] = tid;
            atomicAdd(&s_nvalid, 1);
        }
    }
    __syncthreads();

    // ---- greedy keep, wave 0: lane r holds rank-r data; readlane broadcasts ----
    if (tid < 64) {
        const int nv = s_nvalid;
        int bb0 = -1, bb1 = -1;
        unsigned long long r00 = 0, r01 = 0, r10 = 0, r11 = 0;
        if (tid < nv) {
            bb0 = boxorder[tid];
            r00 = iouRow[bb0 * 2]; r01 = iouRow[bb0 * 2 + 1];
        }
        if (tid + 64 < nv) {
            bb1 = boxorder[tid + 64];
            r10 = iouRow[bb1 * 2]; r11 = iouRow[bb1 * 2 + 1];
        }
        unsigned long long sup0 = 0, sup1 = 0, k0 = 0, k1 = 0;
        for (int r = 0; r < nv; ++r) {
            int bb; unsigned long long rw0, rw1;
            if (r < 64) {
                bb  = __builtin_amdgcn_readlane(bb0, r);
                rw0 = rl64(r00, r); rw1 = rl64(r01, r);
            } else {
                bb  = __builtin_amdgcn_readlane(bb1, r - 64);
                rw0 = rl64(r10, r - 64); rw1 = rl64(r11, r - 64);
            }
            const bool supped = (bb < 64) ? ((sup0 >> bb) & 1ull)
                                          : ((sup1 >> (bb - 64)) & 1ull);
            if (!supped) {
                if (bb < 64) k0 |= 1ull << bb; else k1 |= 1ull << (bb - 64);
                sup0 |= rw0; sup1 |= rw1;
            }
        }
        kept[tid] = (int)((k0 >> tid) & 1ull);
        if (tid < NBOX - 64) kept[tid + 64] = (int)((k1 >> tid) & 1ull);
    }
    __syncthreads();

    // ---- write outputs straight from sorted registers ----
    float* outBoxes = out + b * (NENT * 4);
    float* outProbs = out + BATCH * NENT * 4 + b * NENT;
    float* outCls   = out + BATCH * NENT * 5 + b * NENT;
    #pragma unroll
    for (int i = 0; i < 8; ++i) {
        const int kp = tid * 8 + i;
        if (kp < NENT) {
            const unsigned long long key = e[i];
            const unsigned pb2 = (unsigned)(key >> 32);
            const int idx = (int)(0xFFFFFFFFu - (unsigned)key);
            const int bo  = idx / Cc;
            *reinterpret_cast<float4*>(outBoxes + kp * 4) = bBox[bo];
            outProbs[kp] = (pb2 != 0u && kp == firstpos[bo] && kept[bo])
                             ? __uint_as_float(pb2) : 0.0f;
            outCls[kp] = (float)bCls[bo];
        }
    }
}

extern "C" void kernel_launch(void* const* d_in, const int* in_sizes, int n_in,
                              void* d_out, int out_size, void* d_ws, size_t ws_size,
                              hipStream_t stream)
{
    const float* pred = (const float*)d_in[0];
    float* out = (float*)d_out;
    yolo_nms_kernel<<<BATCH, NT, 0, stream>>>(pred, out);
}

// Round 6
// 32.580 us; speedup vs baseline: 1.3492x; 1.3492x over previous
//
#include <hip/hip_runtime.h>

// YOLO decode + 4-pass ballot-based LSD radix sort + box-level greedy NMS.
// One block (1024 threads) per batch item. S=7,B=2,C=20 -> 98 boxes, 1960 entries.
// Sort: stable ascending on complemented prob bytes == (prob desc, idx asc) exact.

constexpr int S_  = 7;
constexpr int Cc  = 20;
constexpr int NBOX  = 98;
constexpr int NENT  = 1960;
constexpr int NPAD  = 2048;
constexpr int LPRED = 1470;
constexpr int BATCH = 16;
constexpr float IOU_THR_  = 0.1f;
constexpr float PROB_THR_ = 8e-25f;

__device__ __forceinline__ unsigned long long rl64(unsigned long long v, int l)
{
    unsigned lo = (unsigned)__builtin_amdgcn_readlane((int)(unsigned)v, l);
    unsigned hi = (unsigned)__builtin_amdgcn_readlane((int)(unsigned)(v >> 32), l);
    return ((unsigned long long)hi << 32) | lo;
}

__global__ __launch_bounds__(1024)
void yolo_nms_kernel(const float* __restrict__ pred_all, float* __restrict__ out)
{
    const int b    = blockIdx.x;
    const int tid  = threadIdx.x;
    const int wv   = tid >> 6, lane = tid & 63;
    const unsigned long long lt = (1ull << lane) - 1ull;
    const unsigned long long le = lt | (1ull << lane);
    const float* pred = pred_all + b * LPRED;

    __shared__ float s_pred[LPRED];
    __shared__ unsigned int   sProb[2][NPAD];              // payload: prob bits
    __shared__ unsigned short sIdx [2][NPAD];              // payload: entry idx
    __shared__ alignas(16) unsigned short sHist[2][16 * 256]; // [wave*256+digit]
    __shared__ unsigned int   sTot[256];                   // totals -> base (in place)
    __shared__ float bXh[NBOX], bXl[NBOX], bYh[NBOX], bYl[NBOX], bA[NBOX];
    __shared__ float4 bBox[NBOX];
    __shared__ int   bCls[NBOX];
    __shared__ unsigned long long iouRow[NBOX * 2];
    __shared__ int firstpos[NBOX], boxorder[NBOX], kept[NBOX], s_nvalid;

    // ---- stage prediction + init ----
    for (int i = tid; i < LPRED; i += 1024) s_pred[i] = pred[i];
    reinterpret_cast<unsigned long long*>(sHist[0])[tid] = 0ull;   // zero hist buf 0
    if (tid == 0) s_nvalid = 0;
    if (tid < NBOX) { kept[tid] = 0; firstpos[tid] = 0x7FFFFFFF; }
    __syncthreads();

    // ---- decode 98 boxes (reference float32 op order) + first-class-over-thr ----
    if (tid < NBOX) {
        const int bo = tid, cell = bo >> 1;
        const int ci = cell / S_, cj = cell % S_;
        const float bx = s_pred[1078 + bo * 4 + 0];
        const float by = s_pred[1078 + bo * 4 + 1];
        const float bw = s_pred[1078 + bo * 4 + 2];
        const float bh = s_pred[1078 + bo * 4 + 3];
        const float x = (bx + (float)ci) / 7.0f * 448.0f;
        const float y = (by + (float)cj) / 7.0f * 448.0f;
        const float w = bw * bw * 448.0f;
        const float h = bh * bh * 448.0f;
        bBox[bo] = make_float4(x, y, w, h);
        bXh[bo] = x + 0.5f * w;  bXl[bo] = x - 0.5f * w;
        bYh[bo] = y + 0.5f * h;  bYl[bo] = y - 0.5f * h;
        bA[bo]  = w * h;
        const float conf = s_pred[980 + bo];
        int cls = 0;
        for (int c = 0; c < Cc; ++c)
            if (s_pred[cell * Cc + c] * conf >= PROB_THR_) { cls = c; break; }
        bCls[bo] = cls;
    }

    // ---- initial payload: entry order = idx ascending (stability base) ----
    #pragma unroll
    for (int s = 0; s < 2; ++s) {
        const int e = 2 * tid + s;
        unsigned pb = 0u;
        if (e < NENT) {
            const int bo = e / Cc, c = e - bo * Cc, cell = bo >> 1;
            const float ep = s_pred[cell * Cc + c] * s_pred[980 + bo];
            if (ep >= PROB_THR_) pb = __float_as_uint(ep);
        }
        sProb[0][e] = pb;
        sIdx[0][e]  = (unsigned short)e;
    }
    __syncthreads();

    // ---- pairwise IoU rows via ballot (iouRow read only after later barriers) ----
    for (int r = wv; r < NBOX; r += 16) {
        const float rXh = bXh[r], rXl = bXl[r], rYh = bYh[r], rYl = bYl[r], rA = bA[r];
        bool s1 = false, s2 = false;
        {
            const int j = lane;
            const float tb = fminf(rXh, bXh[j]) - fmaxf(rXl, bXl[j]);
            const float lr = fminf(rYh, bYh[j]) - fmaxf(rYl, bYl[j]);
            const float inter = (tb < 0.0f || lr < 0.0f) ? 0.0f : tb * lr;
            const float iou = inter / (rA + bA[j] - inter);   // 0/0 -> NaN -> false
            s1 = (iou > IOU_THR_);
        }
        if (lane + 64 < NBOX) {
            const int j = lane + 64;
            const float tb = fminf(rXh, bXh[j]) - fmaxf(rXl, bXl[j]);
            const float lr = fminf(rYh, bYh[j]) - fmaxf(rYl, bYl[j]);
            const float inter = (tb < 0.0f || lr < 0.0f) ? 0.0f : tb * lr;
            const float iou = inter / (rA + bA[j] - inter);
            s2 = (iou > IOU_THR_);
        }
        const unsigned long long m1 = __ballot(s1);
        const unsigned long long m2 = __ballot(s2);
        if (lane == 0) { iouRow[r * 2] = m1; iouRow[r * 2 + 1] = m2; }
    }

    // ---- radix sort: 4 passes, stable, ascending on complemented digits ----
    int src = 0;
    #pragma unroll
    for (int pass = 0; pass < 4; ++pass) {
        const int hb  = pass & 1;
        const int dst = src ^ 1;
        const int sh  = pass * 8;

        const unsigned q0 = sProb[src][2 * tid];
        const unsigned q1 = sProb[src][2 * tid + 1];
        const unsigned short j0 = sIdx[src][2 * tid];
        const unsigned short j1 = sIdx[src][2 * tid + 1];
        const unsigned d0 = 0xFFu ^ ((q0 >> sh) & 0xFFu);
        const unsigned d1 = 0xFFu ^ ((q1 >> sh) & 0xFFu);

        // 8-bit match masks via shared ballots: mXY = lanes whose elemY digit == my elemX digit
        unsigned long long mAA = ~0ull, mAB = ~0ull, mBA = ~0ull, mBB = ~0ull;
        #pragma unroll
        for (int bit = 0; bit < 8; ++bit) {
            const unsigned long long ba = __ballot((d0 >> bit) & 1u);
            const unsigned long long bb = __ballot((d1 >> bit) & 1u);
            mAA &= ((d0 >> bit) & 1u) ? ba : ~ba;
            mAB &= ((d0 >> bit) & 1u) ? bb : ~bb;
            mBA &= ((d1 >> bit) & 1u) ? ba : ~ba;
            mBB &= ((d1 >> bit) & 1u) ? bb : ~bb;
        }
        // element order within wave: pos = 2*lane + slot (A=slot0, B=slot1)
        const int rank0 = __popcll(mAA & lt) + __popcll(mAB & lt);
        const int rank1 = __popcll(mBA & le) + __popcll(mBB & lt);
        sHist[hb][wv * 256 + d0] = (unsigned short)(__popcll(mAA) + __popcll(mAB));
        sHist[hb][wv * 256 + d1] = (unsigned short)(__popcll(mBA) + __popcll(mBB));
        __syncthreads();

        // per-digit wave-prefix (exclusive over waves) + digit totals
        if (tid < 256) {
            unsigned run = 0;
            unsigned short pf[16];
            #pragma unroll
            for (int w = 0; w < 16; ++w) {
                const unsigned c = sHist[hb][w * 256 + tid];
                pf[w] = (unsigned short)run;
                run += c;
            }
            #pragma unroll
            for (int w = 0; w < 16; ++w) sHist[hb][w * 256 + tid] = pf[w];
            sTot[tid] = run;
        }
        __syncthreads();

        // exclusive scan of 256 digit totals -> base (wave 0, shuffle scan)
        if (wv == 0) {
            const unsigned v0 = sTot[4 * lane],     v1 = sTot[4 * lane + 1];
            const unsigned v2 = sTot[4 * lane + 2], v3 = sTot[4 * lane + 3];
            const unsigned sm = v0 + v1 + v2 + v3;
            unsigned inc = sm;
            #pragma unroll
            for (int off = 1; off < 64; off <<= 1) {
                const unsigned t = __shfl_up(inc, off, 64);
                if (lane >= off) inc += t;
            }
            const unsigned ex = inc - sm;
            sTot[4 * lane]     = ex;
            sTot[4 * lane + 1] = ex + v0;
            sTot[4 * lane + 2] = ex + v0 + v1;
            sTot[4 * lane + 3] = ex + v0 + v1 + v2;
        }
        __syncthreads();

        // stable scatter
        const unsigned pos0 = sTot[d0] + sHist[hb][wv * 256 + d0] + (unsigned)rank0;
        const unsigned pos1 = sTot[d1] + sHist[hb][wv * 256 + d1] + (unsigned)rank1;
        sProb[dst][pos0] = q0;  sIdx[dst][pos0] = j0;
        sProb[dst][pos1] = q1;  sIdx[dst][pos1] = j1;
        if (pass == 3) {
            if (q0) atomicMin(&firstpos[j0 / Cc], (int)pos0);
            if (q1) atomicMin(&firstpos[j1 / Cc], (int)pos1);
        } else {
            reinterpret_cast<unsigned long long*>(sHist[hb ^ 1])[tid] = 0ull;
        }
        __syncthreads();
        src = dst;
    }
    // after 4 passes sorted data is in buffer 0; firstpos complete

    // ---- rank boxes by firstpos (distinct -> permutation) ----
    if (tid < NBOX) {
        const int fp = firstpos[tid];
        if (fp != 0x7FFFFFFF) {
            int r = 0;
            for (int b2 = 0; b2 < NBOX; ++b2) r += (firstpos[b2] < fp) ? 1 : 0;
            boxorder[r] = tid;
            atomicAdd(&s_nvalid, 1);
        }
    }
    __syncthreads();

    // ---- greedy keep, wave 0: lane r holds rank-r data; readlane broadcasts ----
    if (tid < 64) {
        const int nv = s_nvalid;
        int bb0 = -1, bb1 = -1;
        unsigned long long r00 = 0, r01 = 0, r10 = 0, r11 = 0;
        if (tid < nv) {
            bb0 = boxorder[tid];
            r00 = iouRow[bb0 * 2]; r01 = iouRow[bb0 * 2 + 1];
        }
        if (tid + 64 < nv) {
            bb1 = boxorder[tid + 64];
            r10 = iouRow[bb1 * 2]; r11 = iouRow[bb1 * 2 + 1];
        }
        unsigned long long sup0 = 0, sup1 = 0, k0 = 0, k1 = 0;
        for (int r = 0; r < nv; ++r) {
            int bb; unsigned long long rw0, rw1;
            if (r < 64) {
                bb  = __builtin_amdgcn_readlane(bb0, r);
                rw0 = rl64(r00, r); rw1 = rl64(r01, r);
            } else {
                bb  = __builtin_amdgcn_readlane(bb1, r - 64);
                rw0 = rl64(r10, r - 64); rw1 = rl64(r11, r - 64);
            }
            const bool supped = (bb < 64) ? ((sup0 >> bb) & 1ull)
                                          : ((sup1 >> (bb - 64)) & 1ull);
            if (!supped) {
                if (bb < 64) k0 |= 1ull << bb; else k1 |= 1ull << (bb - 64);
                sup0 |= rw0; sup1 |= rw1;
            }
        }
        kept[tid] = (int)((k0 >> tid) & 1ull);
        if (tid < NBOX - 64) kept[tid + 64] = (int)((k1 >> tid) & 1ull);
    }
    __syncthreads();

    // ---- write outputs: boxes (B,N,4) | probs (B,N) | cls (B,N) ----
    float* outBoxes = out + b * (NENT * 4);
    float* outProbs = out + BATCH * NENT * 4 + b * NENT;
    float* outCls   = out + BATCH * NENT * 5 + b * NENT;
    if (tid < NENT / 2) {
        #pragma unroll
        for (int s = 0; s < 2; ++s) {
            const int kp = 2 * tid + s;
            const unsigned q = sProb[0][kp];
            const int j  = sIdx[0][kp];
            const int bo = j / Cc;
            *reinterpret_cast<float4*>(outBoxes + kp * 4) = bBox[bo];
            outProbs[kp] = (q != 0u && kp == firstpos[bo] && kept[bo])
                             ? __uint_as_float(q) : 0.0f;
            outCls[kp] = (float)bCls[bo];
        }
    }
}

extern "C" void kernel_launch(void* const* d_in, const int* in_sizes, int n_in,
                              void* d_out, int out_size, void* d_ws, size_t ws_size,
                              hipStream_t stream)
{
    const float* pred = (const float*)d_in[0];
    float* out = (float*)d_out;
    yolo_nms_kernel<<<BATCH, 1024, 0, stream>>>(pred, out);
}

// Round 7
// 31.989 us; speedup vs baseline: 1.3741x; 1.0185x over previous
//
#include <hip/hip_runtime.h>

// YOLO decode + 4-pass ballot radix sort (pass 3 scatters straight to global)
// + box-level greedy NMS. One block (1024 threads) per batch item.
// S=7, B=2, C=20 -> 98 boxes, 1960 entries; sort = stable (prob desc, idx asc).

constexpr int S_  = 7;
constexpr int Cc  = 20;
constexpr int NBOX  = 98;
constexpr int NENT  = 1960;
constexpr int NPAD  = 2048;
constexpr int LPRED = 1470;
constexpr int BATCH = 16;
constexpr float IOU_THR_  = 0.1f;
constexpr float PROB_THR_ = 8e-25f;

__device__ __forceinline__ unsigned long long rl64(unsigned long long v, int l)
{
    unsigned lo = (unsigned)__builtin_amdgcn_readlane((int)(unsigned)v, l);
    unsigned hi = (unsigned)__builtin_amdgcn_readlane((int)(unsigned)(v >> 32), l);
    return ((unsigned long long)hi << 32) | lo;
}

__global__ __launch_bounds__(1024)
void yolo_nms_kernel(const float* __restrict__ pred_all, float* __restrict__ out)
{
    const int b    = blockIdx.x;
    const int tid  = threadIdx.x;
    const int wv   = tid >> 6, lane = tid & 63;
    const unsigned long long lt = (1ull << lane) - 1ull;
    const unsigned long long le = lt | (1ull << lane);
    const float* pred = pred_all + b * LPRED;

    float* outBoxes = out + b * (NENT * 4);
    float* outProbs = out + BATCH * NENT * 4 + b * NENT;
    float* outCls   = out + BATCH * NENT * 5 + b * NENT;

    __shared__ float s_pred[LPRED];
    __shared__ unsigned int   sProb[2][NPAD];              // sort key: prob bits
    __shared__ unsigned short sIdx [2][NPAD];              // payload: entry idx
    __shared__ alignas(16) unsigned short sHist[2][16 * 256]; // [wave*256+digit]
    __shared__ unsigned int   sTot[256];                   // digit totals -> base
    __shared__ float bXh[NBOX], bXl[NBOX], bYh[NBOX], bYl[NBOX], bA[NBOX];
    __shared__ float4 bBox[NBOX];
    __shared__ float bClsF[NBOX], bPmax[NBOX];
    __shared__ unsigned long long iouRow[NBOX * 2];
    __shared__ int firstpos[NBOX], boxorder[NBOX], kept[NBOX], s_nvalid;

    // ---- probs zero-fill (coalesced, overlaps with input load latency) ----
    {
        float4* zp = reinterpret_cast<float4*>(outProbs);
        if (tid < NENT / 4) zp[tid] = make_float4(0.f, 0.f, 0.f, 0.f);
    }
    // ---- stage prediction + init ----
    for (int i = tid; i < LPRED; i += 1024) s_pred[i] = pred[i];
    reinterpret_cast<unsigned long long*>(sHist[0])[tid] = 0ull;   // zero hist buf 0
    if (tid == 0) s_nvalid = 0;
    if (tid < NBOX) { kept[tid] = 0; firstpos[tid] = 0x7FFFFFFF; }
    __syncthreads();

    // ---- decode 98 boxes (reference float32 op order) + cls + pmax ----
    if (tid < NBOX) {
        const int bo = tid, cell = bo >> 1;
        const int ci = cell / S_, cj = cell % S_;
        const float bx = s_pred[1078 + bo * 4 + 0];
        const float by = s_pred[1078 + bo * 4 + 1];
        const float bw = s_pred[1078 + bo * 4 + 2];
        const float bh = s_pred[1078 + bo * 4 + 3];
        const float x = (bx + (float)ci) / 7.0f * 448.0f;
        const float y = (by + (float)cj) / 7.0f * 448.0f;
        const float w = bw * bw * 448.0f;
        const float h = bh * bh * 448.0f;
        bBox[bo] = make_float4(x, y, w, h);
        bXh[bo] = x + 0.5f * w;  bXl[bo] = x - 0.5f * w;
        bYh[bo] = y + 0.5f * h;  bYl[bo] = y - 0.5f * h;
        bA[bo]  = w * h;
        const float conf = s_pred[980 + bo];
        unsigned mask = 0u; float pm = 0.f;
        #pragma unroll
        for (int c = 0; c < Cc; ++c) {
            const float ep = s_pred[cell * Cc + c] * conf;
            if (ep >= PROB_THR_) mask |= 1u << c;
            pm = fmaxf(pm, ep);
        }
        bClsF[bo] = (float)(mask ? (__ffs(mask) - 1) : 0);
        bPmax[bo] = pm;    // value of the box's first positive sorted entry
    }

    // ---- initial payload: idx-ascending order (stability base) ----
    #pragma unroll
    for (int s = 0; s < 2; ++s) {
        const int e = 2 * tid + s;
        unsigned pb = 0u;
        if (e < NENT) {
            const int bo = e / Cc, c = e - bo * Cc, cell = bo >> 1;
            const float ep = s_pred[cell * Cc + c] * s_pred[980 + bo];
            if (ep >= PROB_THR_) pb = __float_as_uint(ep);
        }
        sProb[0][e] = pb;
        sIdx[0][e]  = (unsigned short)e;
    }
    __syncthreads();

    // ---- pairwise IoU rows via ballot (iouRow read only after later barriers) ----
    for (int r = wv; r < NBOX; r += 16) {
        const float rXh = bXh[r], rXl = bXl[r], rYh = bYh[r], rYl = bYl[r], rA = bA[r];
        bool s1 = false, s2 = false;
        {
            const int j = lane;
            const float tb = fminf(rXh, bXh[j]) - fmaxf(rXl, bXl[j]);
            const float lr = fminf(rYh, bYh[j]) - fmaxf(rYl, bYl[j]);
            const float inter = (tb < 0.0f || lr < 0.0f) ? 0.0f : tb * lr;
            const float iou = inter / (rA + bA[j] - inter);   // 0/0 -> NaN -> false
            s1 = (iou > IOU_THR_);
        }
        if (lane + 64 < NBOX) {
            const int j = lane + 64;
            const float tb = fminf(rXh, bXh[j]) - fmaxf(rXl, bXl[j]);
            const float lr = fminf(rYh, bYh[j]) - fmaxf(rYl, bYl[j]);
            const float inter = (tb < 0.0f || lr < 0.0f) ? 0.0f : tb * lr;
            const float iou = inter / (rA + bA[j] - inter);
            s2 = (iou > IOU_THR_);
        }
        const unsigned long long m1 = __ballot(s1);
        const unsigned long long m2 = __ballot(s2);
        if (lane == 0) { iouRow[r * 2] = m1; iouRow[r * 2 + 1] = m2; }
    }

    // ---- radix sort: 4 passes, stable ascending on complemented digits ----
    int src = 0;
    #pragma unroll
    for (int pass = 0; pass < 4; ++pass) {
        const int hb  = pass & 1;
        const int dst = src ^ 1;
        const int sh  = pass * 8;

        const unsigned q0 = sProb[src][2 * tid];
        const unsigned q1 = sProb[src][2 * tid + 1];
        const unsigned short j0 = sIdx[src][2 * tid];
        const unsigned short j1 = sIdx[src][2 * tid + 1];
        const unsigned d0 = 0xFFu ^ ((q0 >> sh) & 0xFFu);
        const unsigned d1 = 0xFFu ^ ((q1 >> sh) & 0xFFu);

        // 8-bit match masks via ballots
        unsigned long long mAA = ~0ull, mAB = ~0ull, mBA = ~0ull, mBB = ~0ull;
        #pragma unroll
        for (int bit = 0; bit < 8; ++bit) {
            const unsigned long long ba = __ballot((d0 >> bit) & 1u);
            const unsigned long long bb = __ballot((d1 >> bit) & 1u);
            mAA &= ((d0 >> bit) & 1u) ? ba : ~ba;
            mAB &= ((d0 >> bit) & 1u) ? bb : ~bb;
            mBA &= ((d1 >> bit) & 1u) ? ba : ~ba;
            mBB &= ((d1 >> bit) & 1u) ? bb : ~bb;
        }
        // in-wave stable ranks; element order = 2*lane + slot
        const int rank0 = __popcll(mAA & lt) + __popcll(mAB & lt);
        const int rank1 = __popcll(mBA & le) + __popcll(mBB & lt);
        sHist[hb][wv * 256 + d0] = (unsigned short)(__popcll(mAA) + __popcll(mAB));
        sHist[hb][wv * 256 + d1] = (unsigned short)(__popcll(mBA) + __popcll(mBB));
        __syncthreads();

        // per-digit exclusive wave-prefix + digit totals
        if (tid < 256) {
            unsigned run = 0;
            unsigned short pf[16];
            #pragma unroll
            for (int w = 0; w < 16; ++w) {
                const unsigned c = sHist[hb][w * 256 + tid];
                pf[w] = (unsigned short)run;
                run += c;
            }
            #pragma unroll
            for (int w = 0; w < 16; ++w) sHist[hb][w * 256 + tid] = pf[w];
            sTot[tid] = run;
        }
        __syncthreads();

        // exclusive scan of 256 digit totals (wave 0)
        if (wv == 0) {
            const unsigned v0 = sTot[4 * lane],     v1 = sTot[4 * lane + 1];
            const unsigned v2 = sTot[4 * lane + 2], v3 = sTot[4 * lane + 3];
            const unsigned sm = v0 + v1 + v2 + v3;
            unsigned inc = sm;
            #pragma unroll
            for (int off = 1; off < 64; off <<= 1) {
                const unsigned t = __shfl_up(inc, off, 64);
                if (lane >= off) inc += t;
            }
            const unsigned ex = inc - sm;
            sTot[4 * lane]     = ex;
            sTot[4 * lane + 1] = ex + v0;
            sTot[4 * lane + 2] = ex + v0 + v1;
            sTot[4 * lane + 3] = ex + v0 + v1 + v2;
        }
        __syncthreads();

        const unsigned pos0 = sTot[d0] + sHist[hb][wv * 256 + d0] + (unsigned)rank0;
        const unsigned pos1 = sTot[d1] + sHist[hb][wv * 256 + d1] + (unsigned)rank1;

        if (pass < 3) {
            // stable scatter to LDS
            sProb[dst][pos0] = q0;  sIdx[dst][pos0] = j0;
            sProb[dst][pos1] = q1;  sIdx[dst][pos1] = j1;
            reinterpret_cast<unsigned long long*>(sHist[hb ^ 1])[tid] = 0ull;
        } else {
            // final positions: scatter boxes/cls straight to global.
            // pads (j>=NENT) provably land at pos>=NENT (all-zero key, idx-stable).
            if (j0 < NENT) {
                const int bo = j0 / Cc;
                *reinterpret_cast<float4*>(outBoxes + pos0 * 4) = bBox[bo];
                outCls[pos0] = bClsF[bo];
                if (q0) atomicMin(&firstpos[bo], (int)pos0);
            }
            if (j1 < NENT) {
                const int bo = j1 / Cc;
                *reinterpret_cast<float4*>(outBoxes + pos1 * 4) = bBox[bo];
                outCls[pos1] = bClsF[bo];
                if (q1) atomicMin(&firstpos[bo], (int)pos1);
            }
        }
        __syncthreads();
        src = dst;
    }

    // ---- rank boxes by firstpos (distinct -> permutation) ----
    if (tid < NBOX) {
        const int fp = firstpos[tid];
        if (fp != 0x7FFFFFFF) {
            int r = 0;
            for (int b2 = 0; b2 < NBOX; ++b2) r += (firstpos[b2] < fp) ? 1 : 0;
            boxorder[r] = tid;
            atomicAdd(&s_nvalid, 1);
        }
    }
    __syncthreads();

    // ---- greedy keep, wave 0: lane r holds rank-r data; readlane broadcasts ----
    if (tid < 64) {
        const int nv = s_nvalid;
        int bb0 = -1, bb1 = -1;
        unsigned long long r00 = 0, r01 = 0, r10 = 0, r11 = 0;
        if (tid < nv) {
            bb0 = boxorder[tid];
            r00 = iouRow[bb0 * 2]; r01 = iouRow[bb0 * 2 + 1];
        }
        if (tid + 64 < nv) {
            bb1 = boxorder[tid + 64];
            r10 = iouRow[bb1 * 2]; r11 = iouRow[bb1 * 2 + 1];
        }
        unsigned long long sup0 = 0, sup1 = 0, k0 = 0, k1 = 0;
        for (int r = 0; r < nv; ++r) {
            int bb; unsigned long long rw0, rw1;
            if (r < 64) {
                bb  = __builtin_amdgcn_readlane(bb0, r);
                rw0 = rl64(r00, r); rw1 = rl64(r01, r);
            } else {
                bb  = __builtin_amdgcn_readlane(bb1, r - 64);
                rw0 = rl64(r10, r - 64); rw1 = rl64(r11, r - 64);
            }
            const bool supped = (bb < 64) ? ((sup0 >> bb) & 1ull)
                                          : ((sup1 >> (bb - 64)) & 1ull);
            if (!supped) {
                if (bb < 64) k0 |= 1ull << bb; else k1 |= 1ull << (bb - 64);
                sup0 |= rw0; sup1 |= rw1;
            }
        }
        kept[tid] = (int)((k0 >> tid) & 1ull);
        if (tid < NBOX - 64) kept[tid + 64] = (int)((k1 >> tid) & 1ull);
    }
    __syncthreads();

    // ---- sparse probs: kept boxes' first positions get their max e-prob ----
    if (tid < NBOX && kept[tid]) outProbs[firstpos[tid]] = bPmax[tid];
}

extern "C" void kernel_launch(void* const* d_in, const int* in_sizes, int n_in,
                              void* d_out, int out_size, void* d_ws, size_t ws_size,
                              hipStream_t stream)
{
    const float* pred = (const float*)d_in[0];
    float* out = (float*)d_out;
    yolo_nms_kernel<<<BATCH, 1024, 0, stream>>>(pred, out);
}